// Round 8
// baseline (592.122 us; speedup 1.0000x reference)
//
#include <hip/hip_runtime.h>
#include <hip/hip_bf16.h>

// CRF-as-RNN mean-field on MI355X. B=2, L=21, C=3, H=W=96, N=9216, NITERS=5.
//
// w[n][m] = exp2(gs[m] + f_n . fs[m]); per iter P[n][l] = sum_m w[n][m]*MQ[l][m]
// via bf16 MFMA 16x16x32. W generated on the fly into a SINGLE pad-free
// swizzled LDS tile (64x64 bf16, 8KB; 16B-chunk index XOR row&7 on both
// ds_write_b64 and ds_read_b128 — conflict-free: stride-72 layout had a
// structural 4-way read conflict, 3.98M cycles/dispatch). MQ B-fragments
// load straight from global into registers (L1-resident, the R2 component
// that worked) — Mlds deleted, halving LDS-pipe traffic (R7's serializer
// at ~70% busy). Rowsum stays free: B-lane for col 21 (lr==5) is const 1.0
// via select; lanes lr>5 feed discarded cols (clamped row-20 load, harmless).
// Thin lgkm-only barriers (no vmcnt drain); depth-1 FS prefetch; B loads
// issue at tile top, covered by ~300cy of w-gen. VGPR kept <= 64 for
// 8 blocks/CU residency. msg = P/P[21]; Q = softmax_l(-(E0+msg)); MQ = Mu@Q.

#define BB 2
#define LL 21
#define LP (LL + 1)   // Ppart rows: 21 msg cols + 1 rowsum col
#define NNPX 9216
#define NITERS 5
#define LOG2E 1.4426950408889634f

// raw barrier: waits LDS ops of this wave, syncs, does NOT drain vmcnt
#define BARRIER() asm volatile("s_waitcnt lgkmcnt(0)\n\ts_barrier" ::: "memory")

typedef __attribute__((ext_vector_type(8))) short short8;
typedef __attribute__((ext_vector_type(4))) float f32x4;
typedef __attribute__((ext_vector_type(4))) unsigned int u32x4;

static __device__ inline unsigned int pk_bf16(float a, float b) {
    __hip_bfloat162 h = __float22bfloat162_rn(make_float2(a, b));
    unsigned int u;
    __builtin_memcpy(&u, &h, 4);
    return u;
}

// ---------------- prep: features + Q0 + MQ0(bf16) ----------------
__global__ __launch_bounds__(256) void k_prep(
        const float* __restrict__ E0, const float* __restrict__ Refs,
        const float* __restrict__ Mu,
        float4* __restrict__ FN, float4* __restrict__ FS,
        __hip_bfloat16* __restrict__ MQ) {
    __shared__ float muS[LL * LL];
    for (int i = threadIdx.x; i < LL * LL; i += 256) muS[i] = Mu[i];
    __syncthreads();

    int idx = blockIdx.x * 256 + threadIdx.x;      // b*N + n
    int b = idx / NNPX, n = idx % NNPX;

    const float* rb = Refs + (size_t)b * 3 * NNPX + n;
    float r0 = rb[0], r1 = rb[NNPX], r2 = rb[2 * NNPX];
    FN[idx] = make_float4(r0, r1, r2, 0.f);
    float g = -0.5f * (r0 * r0 + r1 * r1 + r2 * r2);
    FS[idx] = make_float4(g * LOG2E, r0 * LOG2E, r1 * LOG2E, r2 * LOG2E);

    const float* eb = E0 + (size_t)b * LL * NNPX + n;
    float x[LL];
    float mx = -1e30f;
    for (int l = 0; l < LL; ++l) { x[l] = -eb[(size_t)l * NNPX]; mx = fmaxf(mx, x[l]); }
    float s = 0.f;
    for (int l = 0; l < LL; ++l) { x[l] = __builtin_amdgcn_exp2f((x[l] - mx) * LOG2E); s += x[l]; }
    float rs = __builtin_amdgcn_rcpf(s);
    for (int l = 0; l < LL; ++l) x[l] *= rs;

    __hip_bfloat16* mq = MQ + (size_t)b * LL * NNPX + n;
    for (int k = 0; k < LL; ++k) {
        float a = 0.f;
        for (int l = 0; l < LL; ++l) a += muS[k * LL + l] * x[l];
        mq[(size_t)k * NNPX] = __float2bfloat16(a);
    }
}

// ---------------- accumulate via MFMA (msg + rowsum fused) ----------------
// grid (288, S): blockIdx.x = b*144 + n-tile (64 rows), blockIdx.y = s.
// Block handles CONTIGUOUS m-tiles [s*T, (s+1)*T), T = 144/S, tiles of 64.
__global__ __launch_bounds__(256, 4) void k_accum(
        const float4* __restrict__ FS, const float4* __restrict__ FN,
        const __hip_bfloat16* __restrict__ MQbf, float* __restrict__ Ppart, int S) {
    // W-tile only: 64 rows x 64 bf16 = 8KB, pad-free, chunk-XOR swizzled.
    // Logical 16B chunk c of row r lives at physical chunk (c ^ (r&7)).
    __shared__ __align__(16) unsigned short Wlds[64 * 64];

    int t = threadIdx.x;
    int rb = blockIdx.x;
    int s  = blockIdx.y;
    int b  = rb / 144;
    int n0 = (rb % 144) * 64;
    int wv = t >> 6, lane = t & 63;
    int lr = lane & 15, g = lane >> 4;

    // w-gen mapping (block-wide): thread owns rows ng+16i (i<4), m-quad mq
    int mq = t & 15;
    int ng = t >> 4;
    float fnx[4], fny[4], fnz[4];
    #pragma unroll
    for (int i = 0; i < 4; ++i) {
        float4 v = FN[b * NNPX + n0 + ng + 16 * i];
        fnx[i] = v.x; fny[i] = v.y; fnz[i] = v.z;
    }

    const int T  = 144 / S;
    const int t0 = s * T;
    const float4* fsb = FS + (size_t)b * NNPX;
    const __hip_bfloat16* mqb = MQbf + (size_t)b * LL * NNPX;

    f32x4 acc0 = {0.f, 0.f, 0.f, 0.f};   // C cols 0..15
    f32x4 acc1 = {0.f, 0.f, 0.f, 0.f};   // C cols 16..21 (22..31 discarded)

    short8 ones8;
    {
        u32x4 o = {0x3F803F80u, 0x3F803F80u, 0x3F803F80u, 0x3F803F80u};
        ones8 = __builtin_bit_cast(short8, o);
    }

    // B row for acc1: lr<5 -> MQ row 16+lr; lr==5 -> ones (rowsum col 21);
    // lr>5 -> clamped row 20 (feeds discarded output cols, harmless)
    int r1 = 16 + lr; if (r1 > 20) r1 = 20;

    int row = wv * 16 + lr;
    // swizzled A-read indices (16B chunks: a0 chunk g, a1 chunk g+4)
    int ia0 = row * 64 + ((g ^ (lr & 7)) << 3);
    int ia1 = row * 64 + (((g + 4) ^ (lr & 7)) << 3);
    // swizzled W-write column (8B granule): chunk mq>>1, half mq&1
    int wq = ng & 7;
    int wcol = (((mq >> 1) ^ wq) << 3) + ((mq & 1) << 2);

    // depth-1 prefetch registers
    float4 fsA0, fsA1, fsA2, fsA3;
    short8 b00, b01, b10, b11;

    auto LOADFS = [&](int tile) {
        int m0 = (t0 + tile) * 64;
        fsA0 = fsb[m0 + 4 * mq + 0]; fsA1 = fsb[m0 + 4 * mq + 1];
        fsA2 = fsb[m0 + 4 * mq + 2]; fsA3 = fsb[m0 + 4 * mq + 3];
    };
    auto LOADB = [&](int tile) {
        const __hip_bfloat16* p0 = mqb + (size_t)lr * NNPX + (t0 + tile) * 64 + g * 8;
        b00 = *(const short8*)p0;
        b01 = *(const short8*)(p0 + 32);
        const __hip_bfloat16* p1 = mqb + (size_t)r1 * NNPX + (t0 + tile) * 64 + g * 8;
        b10 = *(const short8*)p1;
        b11 = *(const short8*)(p1 + 32);
    };
    auto STORE = [&]() {
        #pragma unroll
        for (int i = 0; i < 4; ++i) {
            float w0 = __builtin_amdgcn_exp2f(fsA0.x + fnx[i] * fsA0.y + fny[i] * fsA0.z + fnz[i] * fsA0.w);
            float w1 = __builtin_amdgcn_exp2f(fsA1.x + fnx[i] * fsA1.y + fny[i] * fsA1.z + fnz[i] * fsA1.w);
            float w2 = __builtin_amdgcn_exp2f(fsA2.x + fnx[i] * fsA2.y + fny[i] * fsA2.z + fnz[i] * fsA2.w);
            float w3 = __builtin_amdgcn_exp2f(fsA3.x + fnx[i] * fsA3.y + fny[i] * fsA3.z + fnz[i] * fsA3.w);
            uint2 pk;
            pk.x = pk_bf16(w0, w1);
            pk.y = pk_bf16(w2, w3);
            *(uint2*)&Wlds[(ng + 16 * i) * 64 + wcol] = pk;
        }
    };
    auto MFMA = [&]() {
        short8 a0 = *(const short8*)&Wlds[ia0];
        short8 a1 = *(const short8*)&Wlds[ia1];
        short8 v10 = b10, v11 = b11;
        if (lr == 5) { v10 = ones8; v11 = ones8; }   // rowsum column
        acc0 = __builtin_amdgcn_mfma_f32_16x16x32_bf16(a0, b00, acc0, 0, 0, 0);
        acc0 = __builtin_amdgcn_mfma_f32_16x16x32_bf16(a1, b01, acc0, 0, 0, 0);
        acc1 = __builtin_amdgcn_mfma_f32_16x16x32_bf16(a0, v10, acc1, 0, 0, 0);
        acc1 = __builtin_amdgcn_mfma_f32_16x16x32_bf16(a1, v11, acc1, 0, 0, 0);
    };

    // ---- prologue: FS for tile 0 in flight ----
    LOADFS(0);

    // ---- main loop: 2 thin barriers per tile; single W buffer is safe
    // because each BARRIER's lgkmcnt(0) retires this wave's LDS ops before
    // s_barrier. B loads issue at tile top, land during w-gen (~300cy). ----
    for (int tt = 0; tt < T; ++tt) {
        BARRIER();                       // all waves done reading W(tt-1)
        LOADB(tt);                       // B-fragments -> regs (L1/L2)
        STORE();                         // w-gen (waits FS(tt), counted vmcnt)
        if (tt + 1 < T) LOADFS(tt + 1);  // next tile's FS in flight
        BARRIER();                       // W writes visible
        MFMA();                          // ds_read W + reg B (counted waits)
    }

    // epilogue: C layout col=lane&15, row=(lane>>4)*4+reg
    int col = lane & 15, qr = lane >> 4;
    float* pp = Ppart + ((size_t)(s * BB + b) * LP) * NNPX;
    for (int r = 0; r < 4; ++r) {
        int n = n0 + wv * 16 + qr * 4 + r;
        pp[(size_t)col * NNPX + n] = acc0[r];
        if (col < LP - 16) pp[(size_t)(16 + col) * NNPX + n] = acc1[r];
    }
}

// ---------------- reduce partials + softmax + Potts mix ----------------
template <bool LAST>
__global__ __launch_bounds__(256) void k_softmax(
        const float* __restrict__ E0, const float* __restrict__ Ppart,
        const float* __restrict__ Mu,
        __hip_bfloat16* __restrict__ MQ, float* __restrict__ Out, int S) {
    __shared__ float muS[LL * LL];
    for (int i = threadIdx.x; i < LL * LL; i += 256) muS[i] = Mu[i];
    __syncthreads();

    int idx = blockIdx.x * 256 + threadIdx.x;
    int b = idx / NNPX, n = idx % NNPX;

    float P[LP];
    for (int l = 0; l < LP; ++l) P[l] = 0.f;
    for (int s = 0; s < S; ++s) {
        const float* pp = Ppart + ((size_t)(s * BB + b) * LP) * NNPX + n;
        for (int l = 0; l < LP; ++l) P[l] += pp[(size_t)l * NNPX];
    }
    float rinv = __builtin_amdgcn_rcpf(P[LL]);   // rowsum from MFMA col 21

    const float* eb = E0 + (size_t)b * LL * NNPX + n;
    float mx = -1e30f;
    for (int l = 0; l < LL; ++l) {
        P[l] = -(eb[(size_t)l * NNPX] + P[l] * rinv);
        mx = fmaxf(mx, P[l]);
    }
    float ssum = 0.f;
    for (int l = 0; l < LL; ++l) { P[l] = __builtin_amdgcn_exp2f((P[l] - mx) * LOG2E); ssum += P[l]; }
    float rs = __builtin_amdgcn_rcpf(ssum);
    for (int l = 0; l < LL; ++l) P[l] *= rs;

    if (LAST) {
        float* ob = Out + (size_t)b * LL * NNPX + n;
        for (int l = 0; l < LL; ++l) ob[(size_t)l * NNPX] = P[l];
    } else {
        __hip_bfloat16* mq = MQ + (size_t)b * LL * NNPX + n;
        for (int k = 0; k < LL; ++k) {
            float a = 0.f;
            for (int l = 0; l < LL; ++l) a += muS[k * LL + l] * P[l];
            mq[(size_t)k * NNPX] = __float2bfloat16(a);
        }
    }
}

extern "C" void kernel_launch(void* const* d_in, const int* in_sizes, int n_in,
                              void* d_out, int out_size, void* d_ws, size_t ws_size,
                              hipStream_t stream) {
    const float* E0   = (const float*)d_in[0];
    const float* Refs = (const float*)d_in[1];
    const float* Mu   = (const float*)d_in[2];
    float* out = (float*)d_out;

    char* w = (char*)d_ws;
    size_t off = 0;
    auto alloc = [&](size_t bytes) {
        void* p = w + off;
        off += (bytes + 255) & ~(size_t)255;
        return p;
    };
    float4* FN     = (float4*)alloc((size_t)BB * NNPX * sizeof(float4));
    float4* FS     = (float4*)alloc((size_t)BB * NNPX * sizeof(float4));
    __hip_bfloat16* MQbf = (__hip_bfloat16*)alloc((size_t)BB * LL * NNPX * sizeof(__hip_bfloat16));

    // m-split S (divisor of 144, capped at 8) whose partial buffer fits in ws
    size_t per = (size_t)BB * LP * NNPX * sizeof(float);
    size_t avail = ws_size > off ? ws_size - off : 0;
    int Smax = (int)(avail / (per + 256));
    static const int divs[] = {8, 6, 4, 3, 2, 1};
    int S = 1;
    for (int i = 0; i < 6; ++i) if (divs[i] <= Smax) { S = divs[i]; break; }
    float* Ppart = (float*)alloc((size_t)S * per);

    k_prep<<<BB * NNPX / 256, 256, 0, stream>>>(E0, Refs, Mu, FN, FS, MQbf);
    for (int it = 0; it < NITERS; ++it) {
        k_accum<<<dim3(288, S), 256, 0, stream>>>(FS, FN, MQbf, Ppart, S);
        if (it == NITERS - 1)
            k_softmax<true><<<BB * NNPX / 256, 256, 0, stream>>>(E0, Ppart, Mu, MQbf, out, S);
        else
            k_softmax<false><<<BB * NNPX / 256, 256, 0, stream>>>(E0, Ppart, Mu, MQbf, out, S);
    }
}

// Round 9
// 404.044 us; speedup vs baseline: 1.4655x; 1.4655x over previous
//
#include <hip/hip_runtime.h>
#include <hip/hip_bf16.h>

// CRF-as-RNN mean-field on MI355X. B=2, L=21, C=3, H=W=96, N=9216, NITERS=5.
//
// w[n][m] = exp2(gs[m] + f_n . fs[m]); per iter P[n][l] = sum_m w[n][m]*MQ[l][m]
// via bf16 MFMA 16x16x32. R8 lesson: B-frags MUST be LDS-staged (global
// scatter = L1 amplification, 104us); R7 budget: ~500cy VALU-issue per
// wave-tile, only ~144 core w-gen => ~70% per-tile overhead. This round:
// 128 n-rows per block (each wave owns 32 rows = 2 row-halves) with m-tile
// still 64 -> per unit work, B-frag LDS reads, global-load instrs, loop +
// barrier overhead all HALVE (B frags are shared across the wave's 2 row
// halves). W lives in 2x 64x64 pad-free XOR-swizzled LDS tiles (R8-proven
// zero-conflict pattern); MQ staged coalesced as R7 with const rows 21..31
// (row 21 = 1.0 -> MFMA col 21 = rowsum(W) free). Thin lgkm-only barriers,
// depth-1 prefetch. msg = P/P[21]; Q = softmax_l(-(E0+msg)); MQ = Mu@Q.

#define BB 2
#define LL 21
#define LP (LL + 1)   // Ppart rows: 21 msg cols + 1 rowsum col
#define NNPX 9216
#define NITERS 5
#define LOG2E 1.4426950408889634f

// raw barrier: waits LDS ops of this wave, syncs, does NOT drain vmcnt
#define BARRIER() asm volatile("s_waitcnt lgkmcnt(0)\n\ts_barrier" ::: "memory")

typedef __attribute__((ext_vector_type(8))) short short8;
typedef __attribute__((ext_vector_type(4))) float f32x4;

static __device__ inline unsigned int pk_bf16(float a, float b) {
    __hip_bfloat162 h = __float22bfloat162_rn(make_float2(a, b));
    unsigned int u;
    __builtin_memcpy(&u, &h, 4);
    return u;
}

// ---------------- prep: features + Q0 + MQ0(bf16) ----------------
__global__ __launch_bounds__(256) void k_prep(
        const float* __restrict__ E0, const float* __restrict__ Refs,
        const float* __restrict__ Mu,
        float4* __restrict__ FN, float4* __restrict__ FS,
        __hip_bfloat16* __restrict__ MQ) {
    __shared__ float muS[LL * LL];
    for (int i = threadIdx.x; i < LL * LL; i += 256) muS[i] = Mu[i];
    __syncthreads();

    int idx = blockIdx.x * 256 + threadIdx.x;      // b*N + n
    int b = idx / NNPX, n = idx % NNPX;

    const float* rb = Refs + (size_t)b * 3 * NNPX + n;
    float r0 = rb[0], r1 = rb[NNPX], r2 = rb[2 * NNPX];
    FN[idx] = make_float4(r0, r1, r2, 0.f);
    float g = -0.5f * (r0 * r0 + r1 * r1 + r2 * r2);
    FS[idx] = make_float4(g * LOG2E, r0 * LOG2E, r1 * LOG2E, r2 * LOG2E);

    const float* eb = E0 + (size_t)b * LL * NNPX + n;
    float x[LL];
    float mx = -1e30f;
    for (int l = 0; l < LL; ++l) { x[l] = -eb[(size_t)l * NNPX]; mx = fmaxf(mx, x[l]); }
    float s = 0.f;
    for (int l = 0; l < LL; ++l) { x[l] = __builtin_amdgcn_exp2f((x[l] - mx) * LOG2E); s += x[l]; }
    float rs = __builtin_amdgcn_rcpf(s);
    for (int l = 0; l < LL; ++l) x[l] *= rs;

    __hip_bfloat16* mq = MQ + (size_t)b * LL * NNPX + n;
    for (int k = 0; k < LL; ++k) {
        float a = 0.f;
        for (int l = 0; l < LL; ++l) a += muS[k * LL + l] * x[l];
        mq[(size_t)k * NNPX] = __float2bfloat16(a);
    }
}

// ---------------- accumulate via MFMA (msg + rowsum fused) ----------------
// grid (144, S): blockIdx.x = b*72 + n-tile (128 rows), blockIdx.y = s.
// Block handles CONTIGUOUS m-tiles [s*T, (s+1)*T), T = 144/S, tiles of 64.
// Wave wv owns n-rows [wv*32, wv*32+32): 2 row-halves sharing B fragments.
__global__ __launch_bounds__(256, 4) void k_accum(
        const float4* __restrict__ FS, const float4* __restrict__ FN,
        const unsigned int* __restrict__ MQbf, float* __restrict__ Ppart, int S) {
    // W: 2x 64rows x 64 bf16 pad-free, 16B-chunk XOR-swizzled (zero-conflict,
    // R8-proven). M: 32 l x 72 k bf16, rows 21..31 constant (21 = 1.0).
    __shared__ __align__(16) unsigned short Wlds[2][64 * 64];
    __shared__ __align__(16) unsigned short Mlds[32 * 72];

    int t = threadIdx.x;
    int rb = blockIdx.x;
    int s  = blockIdx.y;
    int b  = rb / 72;
    int n0 = (rb % 72) * 128;
    int wv = t >> 6, lane = t & 63;
    int lr = lane & 15, g = lane >> 4;

    // one-time init of constant B rows: row 21 = 1.0 (rowsum), 22..31 = 0
    for (int i = t; i < 11 * 32; i += 256) {
        int r = 21 + (i >> 5), d = i & 31;
        ((unsigned int*)&Mlds[r * 72])[d] = (r == 21) ? 0x3F803F80u : 0u;
    }

    // w-gen mapping: thread owns rows ng + 16*i (i<8), m-quad mq (4 m)
    int mq = t & 15;
    int ng = t >> 4;
    float fnx[8], fny[8], fnz[8];
    #pragma unroll
    for (int i = 0; i < 8; ++i) {
        float4 v = FN[b * NNPX + n0 + ng + 16 * i];
        fnx[i] = v.x; fny[i] = v.y; fnz[i] = v.z;
    }

    const int T  = 144 / S;
    const int t0 = s * T;
    const float4* fsb = FS + (size_t)b * NNPX;
    const unsigned int* mqb = MQbf + (size_t)b * LL * (NNPX / 2);

    // MQ stage ownership: dwords idx = t + 256*r (r<3), idx < 21*32 = 672
    int sl0 = t >> 5, sm0 = t & 31;
    int sl1 = (t + 256) >> 5, sm1 = (t + 256) & 31;
    int sl2 = (t + 512) >> 5, sm2 = (t + 512) & 31;   // valid iff t<160

    f32x4 acc0  = {0.f, 0.f, 0.f, 0.f};   // rows wv*32+lr..    cols 0..15
    f32x4 acc1  = {0.f, 0.f, 0.f, 0.f};   //                    cols 16..21
    f32x4 acc0b = {0.f, 0.f, 0.f, 0.f};   // rows wv*32+16+lr.. cols 0..15
    f32x4 acc1b = {0.f, 0.f, 0.f, 0.f};   //                    cols 16..21

    // W-write swizzle (per-thread constant): logical chunk mq>>1 of row r
    // lives at physical chunk (mq>>1)^(r&7); r&7 == ng&7 for all i.
    int wcol = ((((mq >> 1) ^ (ng & 7)) << 3) + ((mq & 1) << 2));

    // A-read swizzled offsets (per-wave-half constant)
    int half  = wv >> 1;
    int rloc  = (wv & 1) * 32 + lr;          // local row of first half
    int ia0 = rloc * 64 + ((g ^ (lr & 7)) << 3);
    int ia1 = rloc * 64 + (((g + 4) ^ (lr & 7)) << 3);
    int ib0 = (rloc + 16) * 64 + ((g ^ (lr & 7)) << 3);
    int ib1 = (rloc + 16) * 64 + (((g + 4) ^ (lr & 7)) << 3);

    // depth-1 prefetch registers
    float4 fsA0, fsA1, fsA2, fsA3;
    unsigned int mrA0, mrA1, mrA2;

    auto LOAD = [&](int tile) {
        int m0 = (t0 + tile) * 64;
        fsA0 = fsb[m0 + 4 * mq + 0]; fsA1 = fsb[m0 + 4 * mq + 1];
        fsA2 = fsb[m0 + 4 * mq + 2]; fsA3 = fsb[m0 + 4 * mq + 3];
        int mo0 = (t0 + tile) * 32;
        mrA0 = mqb[(size_t)sl0 * (NNPX / 2) + mo0 + sm0];
        mrA1 = mqb[(size_t)sl1 * (NNPX / 2) + mo0 + sm1];
        if (t < 160) mrA2 = mqb[(size_t)sl2 * (NNPX / 2) + mo0 + sm2];
    };
    auto STORE = [&]() {
        ((unsigned int*)&Mlds[sl0 * 72])[sm0] = mrA0;
        ((unsigned int*)&Mlds[sl1 * 72])[sm1] = mrA1;
        if (t < 160) ((unsigned int*)&Mlds[sl2 * 72])[sm2] = mrA2;
        #pragma unroll
        for (int i = 0; i < 8; ++i) {
            float w0 = __builtin_amdgcn_exp2f(fsA0.x + fnx[i] * fsA0.y + fny[i] * fsA0.z + fnz[i] * fsA0.w);
            float w1 = __builtin_amdgcn_exp2f(fsA1.x + fnx[i] * fsA1.y + fny[i] * fsA1.z + fnz[i] * fsA1.w);
            float w2 = __builtin_amdgcn_exp2f(fsA2.x + fnx[i] * fsA2.y + fny[i] * fsA2.z + fnz[i] * fsA2.w);
            float w3 = __builtin_amdgcn_exp2f(fsA3.x + fnx[i] * fsA3.y + fny[i] * fsA3.z + fnz[i] * fsA3.w);
            uint2 pk;
            pk.x = pk_bf16(w0, w1);
            pk.y = pk_bf16(w2, w3);
            int r = ng + 16 * i;                       // global tile row
            *(uint2*)&Wlds[i >> 2][(r & 63) * 64 + wcol] = pk;
        }
    };
    auto MFMA = [&]() {
        // shared B fragments (one set serves both row-halves)
        short8 b00 = *(const short8*)&Mlds[lr * 72 + g * 8];
        short8 b01 = *(const short8*)&Mlds[lr * 72 + g * 8 + 32];
        short8 b10 = *(const short8*)&Mlds[(16 + lr) * 72 + g * 8];
        short8 b11 = *(const short8*)&Mlds[(16 + lr) * 72 + g * 8 + 32];
        short8 a0 = *(const short8*)&Wlds[half][ia0];
        short8 a1 = *(const short8*)&Wlds[half][ia1];
        short8 c0 = *(const short8*)&Wlds[half][ib0];
        short8 c1 = *(const short8*)&Wlds[half][ib1];
        acc0  = __builtin_amdgcn_mfma_f32_16x16x32_bf16(a0, b00, acc0,  0, 0, 0);
        acc0  = __builtin_amdgcn_mfma_f32_16x16x32_bf16(a1, b01, acc0,  0, 0, 0);
        acc1  = __builtin_amdgcn_mfma_f32_16x16x32_bf16(a0, b10, acc1,  0, 0, 0);
        acc1  = __builtin_amdgcn_mfma_f32_16x16x32_bf16(a1, b11, acc1,  0, 0, 0);
        acc0b = __builtin_amdgcn_mfma_f32_16x16x32_bf16(c0, b00, acc0b, 0, 0, 0);
        acc0b = __builtin_amdgcn_mfma_f32_16x16x32_bf16(c1, b01, acc0b, 0, 0, 0);
        acc1b = __builtin_amdgcn_mfma_f32_16x16x32_bf16(c0, b10, acc1b, 0, 0, 0);
        acc1b = __builtin_amdgcn_mfma_f32_16x16x32_bf16(c1, b11, acc1b, 0, 0, 0);
    };

    // ---- prologue: tile 0 loads in flight ----
    LOAD(0);

    // ---- main loop: 2 thin barriers per tile (now per 128 n-rows) ----
    for (int tt = 0; tt < T; ++tt) {
        BARRIER();                       // all waves done reading tile tt-1
        STORE();                         // stage MQ + w-gen (counted vmcnt)
        if (tt + 1 < T) LOAD(tt + 1);    // next tile's globals in flight
        BARRIER();                       // LDS writes visible
        MFMA();                          // 8 MFMA, shared B frags
    }

    // epilogue: C layout col=lane&15, row=(lane>>4)*4+reg, two row-halves
    int col = lane & 15, qr = lane >> 4;
    float* pp = Ppart + ((size_t)(s * BB + b) * LP) * NNPX;
    for (int r = 0; r < 4; ++r) {
        int n = n0 + wv * 32 + qr * 4 + r;
        pp[(size_t)col * NNPX + n] = acc0[r];
        pp[(size_t)col * NNPX + n + 16] = acc0b[r];
        if (col < LP - 16) {
            pp[(size_t)(16 + col) * NNPX + n] = acc1[r];
            pp[(size_t)(16 + col) * NNPX + n + 16] = acc1b[r];
        }
    }
}

// ---------------- reduce partials + softmax + Potts mix ----------------
template <bool LAST>
__global__ __launch_bounds__(256) void k_softmax(
        const float* __restrict__ E0, const float* __restrict__ Ppart,
        const float* __restrict__ Mu,
        __hip_bfloat16* __restrict__ MQ, float* __restrict__ Out, int S) {
    __shared__ float muS[LL * LL];
    for (int i = threadIdx.x; i < LL * LL; i += 256) muS[i] = Mu[i];
    __syncthreads();

    int idx = blockIdx.x * 256 + threadIdx.x;
    int b = idx / NNPX, n = idx % NNPX;

    float P[LP];
    for (int l = 0; l < LP; ++l) P[l] = 0.f;
    for (int s = 0; s < S; ++s) {
        const float* pp = Ppart + ((size_t)(s * BB + b) * LP) * NNPX + n;
        for (int l = 0; l < LP; ++l) P[l] += pp[(size_t)l * NNPX];
    }
    float rinv = __builtin_amdgcn_rcpf(P[LL]);   // rowsum from MFMA col 21

    const float* eb = E0 + (size_t)b * LL * NNPX + n;
    float mx = -1e30f;
    for (int l = 0; l < LL; ++l) {
        P[l] = -(eb[(size_t)l * NNPX] + P[l] * rinv);
        mx = fmaxf(mx, P[l]);
    }
    float ssum = 0.f;
    for (int l = 0; l < LL; ++l) { P[l] = __builtin_amdgcn_exp2f((P[l] - mx) * LOG2E); ssum += P[l]; }
    float rs = __builtin_amdgcn_rcpf(ssum);
    for (int l = 0; l < LL; ++l) P[l] *= rs;

    if (LAST) {
        float* ob = Out + (size_t)b * LL * NNPX + n;
        for (int l = 0; l < LL; ++l) ob[(size_t)l * NNPX] = P[l];
    } else {
        __hip_bfloat16* mq = MQ + (size_t)b * LL * NNPX + n;
        for (int k = 0; k < LL; ++k) {
            float a = 0.f;
            for (int l = 0; l < LL; ++l) a += muS[k * LL + l] * P[l];
            mq[(size_t)k * NNPX] = __float2bfloat16(a);
        }
    }
}

extern "C" void kernel_launch(void* const* d_in, const int* in_sizes, int n_in,
                              void* d_out, int out_size, void* d_ws, size_t ws_size,
                              hipStream_t stream) {
    const float* E0   = (const float*)d_in[0];
    const float* Refs = (const float*)d_in[1];
    const float* Mu   = (const float*)d_in[2];
    float* out = (float*)d_out;

    char* w = (char*)d_ws;
    size_t off = 0;
    auto alloc = [&](size_t bytes) {
        void* p = w + off;
        off += (bytes + 255) & ~(size_t)255;
        return p;
    };
    float4* FN     = (float4*)alloc((size_t)BB * NNPX * sizeof(float4));
    float4* FS     = (float4*)alloc((size_t)BB * NNPX * sizeof(float4));
    __hip_bfloat16* MQbf = (__hip_bfloat16*)alloc((size_t)BB * LL * NNPX * sizeof(__hip_bfloat16));

    // m-split S (divisor of 144, capped at 8) whose partial buffer fits in ws
    size_t per = (size_t)BB * LP * NNPX * sizeof(float);
    size_t avail = ws_size > off ? ws_size - off : 0;
    int Smax = (int)(avail / (per + 256));
    static const int divs[] = {8, 6, 4, 3, 2, 1};
    int S = 1;
    for (int i = 0; i < 6; ++i) if (divs[i] <= Smax) { S = divs[i]; break; }
    float* Ppart = (float*)alloc((size_t)S * per);

    k_prep<<<BB * NNPX / 256, 256, 0, stream>>>(E0, Refs, Mu, FN, FS, MQbf);
    for (int it = 0; it < NITERS; ++it) {
        k_accum<<<dim3(144, S), 256, 0, stream>>>(FS, FN, (const unsigned int*)MQbf, Ppart, S);
        if (it == NITERS - 1)
            k_softmax<true><<<BB * NNPX / 256, 256, 0, stream>>>(E0, Ppart, Mu, MQbf, out, S);
        else
            k_softmax<false><<<BB * NNPX / 256, 256, 0, stream>>>(E0, Ppart, Mu, MQbf, out, S);
    }
}